// Round 7
// baseline (678.615 us; speedup 1.0000x reference)
//
#include <hip/hip_runtime.h>
#include <hip/hip_bf16.h>

typedef __bf16 bf16x8 __attribute__((ext_vector_type(8)));
typedef float f32x4 __attribute__((ext_vector_type(4)));
typedef _Float16 h8 __attribute__((ext_vector_type(8)));
typedef unsigned short u16x8 __attribute__((ext_vector_type(8)));

__device__ inline unsigned short f2b(float x) {
    __hip_bfloat16 h = __float2bfloat16(x);
    return __builtin_bit_cast(unsigned short, h);
}

__device__ inline void gload16(const void* g, void* l) {
    __builtin_amdgcn_global_load_lds(
        (const __attribute__((address_space(1))) unsigned int*)g,
        (__attribute__((address_space(3))) unsigned int*)l, 16, 0, 0);
}

#define BAR  asm volatile("s_barrier" ::: "memory")
#define VMC(N) asm volatile("s_waitcnt vmcnt(" #N ")" ::: "memory")

// reads for one quadrant's A operands (m rows MO, MO+1; both k-halves)
#define RD_A(DST, BASE, MO)                                             \
    DST[0][0] = *(const bf16x8*)((BASE) + (MO) * 1024 + aoff0);         \
    DST[0][1] = *(const bf16x8*)((BASE) + (MO) * 1024 + aoff1);         \
    DST[1][0] = *(const bf16x8*)((BASE) + ((MO) + 1) * 1024 + aoff0);   \
    DST[1][1] = *(const bf16x8*)((BASE) + ((MO) + 1) * 1024 + aoff1);

#define RD_B(DST, BASE)                                                 \
    _Pragma("unroll")                                                   \
    for (int n_ = 0; n_ < 4; ++n_) {                                    \
        DST[n_][0] = *(const bf16x8*)((BASE) + n_ * 1024 + aoff0);      \
        DST[n_][1] = *(const bf16x8*)((BASE) + n_ * 1024 + aoff1);      \
    }

// 16 MFMA: quadrant m in {MO, MO+1} x 4 n x 2 kk, static acc indices.
// Operands come from frag set (AF,BF) read ONE PHASE EARLIER -> lgkm wait
// finds them already drained (issued under previous MFMA cluster).
#define MFMA_Q(MO, AF, BF)                                              \
    __builtin_amdgcn_s_setprio(1);                                      \
    _Pragma("unroll")                                                   \
    for (int kk_ = 0; kk_ < 2; ++kk_)                                   \
        _Pragma("unroll")                                               \
        for (int mi_ = 0; mi_ < 2; ++mi_)                               \
            _Pragma("unroll")                                           \
            for (int n_ = 0; n_ < 4; ++n_)                              \
                acc[(MO) + mi_][n_] =                                   \
                    __builtin_amdgcn_mfma_f32_16x16x32_bf16(            \
                        AF[mi_][kk_], BF[n_][kk_],                      \
                        acc[(MO) + mi_][n_], 0, 0, 0);                  \
    __builtin_amdgcn_s_setprio(0);

// ---------------------------------------------------------------------------
// NT GEMM: C[M,N] = A[M,K] * B[N,K]^T (+bias), A/B bf16 K-contiguous.
// Read-ahead pipelined schedule: 256x256 tile, BK=64, 512 thr = 8 waves
// (2Mx4N), wave tile 128x64, mfma 16x16x32. LDS = 2 bufs x [A0|A1|B0|B1]
// x 16KiB = 128 KiB. Phase (4 per K-tile, quadrants MO=0,2,4,6):
//   { [seal VMC before BAR at q3]; s_barrier; stage 1 half-tile (2 gload_lds);
//     ds_read NEXT phase's frags into the ALTERNATE register set;
//     MFMA quadrant from CURRENT set }
// Key: reads are issued BEFORE the MFMA cluster (into regs the cluster does
// not use), so they drain on the LDS pipe UNDER the matrix-pipe execution,
// instead of after it (r6 serialized: MFMA issue backpressure delayed the
// following reads). A-sets afA/afB alternate every phase; B-sets bfrE/bfrO
// alternate per K-tile (read once per tile, at the previous tile's q3, after
// that tile's seal barrier). 96 frag VGPRs + 128 acc AGPRs = r3's verified
// footprint (VGPR_Count 128, 2 waves/SIMD).
// Hazards: every LDS overwrite >=1 barrier after its region's reads drained
// (compiler lgkm before each MFMA + barrier chain); q3 seals VMC(2) BEFORE
// the barrier that precedes next-tile reads (vmcnt per-wave + barrier =>
// collective); never 0 mid-loop. Stages: q0/q1: A(next tile); q2/q3:
// B(tile+2). Tail iteration peeled, VMC(0) at its q3(e).
// Swizzle (0-conflict, r2-verified): 16B granule g' = g ^ (row&7); source
// pre-swizzled within the row's 128B line, gload_lds dest linear, ds_read
// applies the same involution.
// EPI: 0 = QKV router (bias, q/k normal, v transposed), 1 = f16*scale (scores),
//      2 = bf16 (PV->ao), 3 = f32+bias (final out)
// ---------------------------------------------------------------------------
template<int EPI, int SWZ>
__global__ __launch_bounds__(512, 2) void gemm_nt(
    const unsigned short* __restrict__ A, const unsigned short* __restrict__ B,
    long aZ, long bZ, int lda, int ldb, int K,
    const float* __restrict__ bias,
    void* __restrict__ C0, void* __restrict__ C1, void* __restrict__ C2,
    long cZ, int ldc, float scale, int gx, int gy)
{
    __shared__ __attribute__((aligned(16))) unsigned short lds[2][4][8192];

    int wgid;
    if (SWZ) {
        const int nwg = (int)gridDim.x;
        const int bid = (int)blockIdx.x;
        const int qch = nwg >> 3, rch = nwg & 7;
        const int xcd = bid & 7, idx = bid >> 3;
        wgid = (xcd < rch ? xcd * (qch + 1)
                          : rch * (qch + 1) + (xcd - rch) * qch) + idx;
    } else {
        wgid = (int)blockIdx.x;
    }
    const int bx = wgid % gx;
    const int rem = wgid / gx;
    const int by = rem % gy;
    const int z = rem / gy;

    const int t = threadIdx.x;
    const int lane = t & 63, wid = t >> 6;
    const int wr = wid >> 2, wc = wid & 3;           // 2 x 4 wave grid
    const int tileM = by * 256, tileN = bx * 256;
    A += (size_t)z * aZ;
    B += (size_t)z * bZ;

    f32x4 acc[8][4] = {};

    // ---- read geometry: frag element k = kk*32 + qw*8 (qw = lane>>4);
    // granule g = kk*4+qw; physical g^(row&7), row&7 == lane&7.
    const int l4 = lane & 15, qw = lane >> 4, sw = lane & 7;
    const int aoff0 = l4 * 64 + ((qw ^ sw) << 3);
    const int aoff1 = l4 * 64 + (((4 | qw) ^ sw) << 3);

    // per-wave LDS read bases (compile-time buffer indices)
    const unsigned short* aB0 = &lds[0][wr][0];
    const unsigned short* aB1 = &lds[1][wr][0];
    const unsigned short* bB0 = &lds[0][2 + (wc >> 1)][0] + (wc & 1) * 4096;
    const unsigned short* bB1 = &lds[1][2 + (wc >> 1)][0] + (wc & 1) * 4096;

    // staging dest bases
    char* const ldsA[2] = {(char*)&lds[0][0][0], (char*)&lds[1][0][0]};
    char* const ldsB[2] = {(char*)&lds[0][2][0], (char*)&lds[1][2][0]};

    // ---- staging geometry: half-tile = 128 rows x 64 K, 2 gload16/thread.
    // row = t>>3 (+64), phys granule = t&7, src granule = (t ^ (t>>3)) & 7.
    const int srow = t >> 3;
    const int sg = ((t ^ (t >> 3)) & 7) << 3;
    const unsigned short* Asrc0 = A + (size_t)(tileM + srow) * lda + sg;
    const unsigned short* Asrc1 = Asrc0 + (size_t)128 * lda;
    const unsigned short* Bsrc0 = B + (size_t)(tileN + srow) * ldb + sg;
    const unsigned short* Bsrc1 = Bsrc0 + (size_t)128 * ldb;

    auto stageA = [&](char* Lb, int koff, int h) {
        char* dst = Lb + h * 16384 + wid * 1024;
        const unsigned short* s = (h ? Asrc1 : Asrc0) + koff;
        gload16(s, dst);
        gload16(s + (size_t)64 * lda, dst + 8192);
    };
    auto stageB = [&](char* Lb, int koff, int h) {
        char* dst = Lb + h * 16384 + wid * 1024;
        const unsigned short* s = (h ? Bsrc1 : Bsrc0) + koff;
        gload16(s, dst);
        gload16(s + (size_t)64 * ldb, dst + 8192);
    };

    const int NT = K >> 6;            // BK=64; K % 128 == 0 here -> NT even
    const int NI = NT >> 1;

    // prologue: tile0 fully + B halves of tile1; seal tile0 (B(1) flies).
    stageA(ldsA[0], 0, 0); stageA(ldsA[0], 0, 1);
    stageB(ldsB[0], 0, 0); stageB(ldsB[0], 0, 1);
    stageB(ldsB[1], 64, 0); stageB(ldsB[1], 64, 1);
    VMC(4);
    BAR;

    bf16x8 afA[2][2], afB[2][2], bfrE[4][2], bfrO[4][2];

    // pre-reads for the first phase (tile 0 sealed above)
    RD_B(bfrE, bB0); RD_A(afA, aB0, 0);

#pragma unroll 1
    for (int i = 0; i < NI - 1; ++i) {
        const int kb = i * 128;
        const int ko = kb + 64, ke2 = kb + 128, ko2 = kb + 192;

        // q0(e)
        BAR; stageA(ldsA[1], ko, 0);
        RD_A(afB, aB0, 2);
        MFMA_Q(0, afA, bfrE)
        // q1(e)
        BAR; stageA(ldsA[1], ko, 1);
        RD_A(afA, aB0, 4);
        MFMA_Q(2, afB, bfrE)
        // q2(e)
        BAR; stageB(ldsB[0], ke2, 0);
        RD_A(afB, aB0, 6);
        MFMA_Q(4, afA, bfrE)
        // q3(e): seal tile o, then read its first frags (B(o) + A(o,Q0))
        VMC(2);
        BAR; stageB(ldsB[0], ke2, 1);
        RD_B(bfrO, bB1); RD_A(afA, aB1, 0);
        MFMA_Q(6, afB, bfrE)
        // q0(o)
        BAR; stageA(ldsA[0], ke2, 0);
        RD_A(afB, aB1, 2);
        MFMA_Q(0, afA, bfrO)
        // q1(o)
        BAR; stageA(ldsA[0], ke2, 1);
        RD_A(afA, aB1, 4);
        MFMA_Q(2, afB, bfrO)
        // q2(o)
        BAR; stageB(ldsB[1], ko2, 0);
        RD_A(afB, aB1, 6);
        MFMA_Q(4, afA, bfrO)
        // q3(o): seal tile e+2, then read its first frags
        VMC(2);
        BAR; stageB(ldsB[1], ko2, 1);
        RD_B(bfrE, bB0); RD_A(afA, aB0, 0);
        MFMA_Q(6, afB, bfrO)
    }

    {   // ---- peeled final iteration (no future B/A stages beyond A(o))
        const int ko = (NI - 1) * 128 + 64;
        // q0(e)
        BAR; stageA(ldsA[1], ko, 0);
        RD_A(afB, aB0, 2);
        MFMA_Q(0, afA, bfrE)
        // q1(e)
        BAR; stageA(ldsA[1], ko, 1);
        RD_A(afA, aB0, 4);
        MFMA_Q(2, afB, bfrE)
        // q2(e)
        BAR;
        RD_A(afB, aB0, 6);
        MFMA_Q(4, afA, bfrE)
        // q3(e): final seal (drain all)
        VMC(0);
        BAR;
        RD_B(bfrO, bB1); RD_A(afA, aB1, 0);
        MFMA_Q(6, afB, bfrE)
        // q0(o)
        BAR;
        RD_A(afB, aB1, 2);
        MFMA_Q(0, afA, bfrO)
        // q1(o)
        BAR;
        RD_A(afA, aB1, 4);
        MFMA_Q(2, afB, bfrO)
        // q2(o)
        BAR;
        RD_A(afB, aB1, 6);
        MFMA_Q(4, afA, bfrO)
        // q3(o)
        MFMA_Q(6, afB, bfrO)
    }

    // epilogue: C/D layout col = lane&15, row = (lane>>4)*4 + j  [m89-verified]
    const int lr = lane >> 4, lc = lane & 15;
#pragma unroll
    for (int m = 0; m < 8; ++m) {
#pragma unroll
        for (int n = 0; n < 4; ++n) {
            f32x4 v = acc[m][n];
            const int col = tileN + wc * 64 + n * 16 + lc;
            const int row0 = tileM + wr * 128 + m * 16 + lr * 4;
            if (EPI == 0) {
                const float bv = bias[col];
                if (col < 2048) {
                    unsigned short* dst = (col < 1024) ? (unsigned short*)C0
                                                       : (unsigned short*)C1;
                    const int cc = col & 1023;
#pragma unroll
                    for (int j = 0; j < 4; ++j)
                        dst[(size_t)(row0 + j) * 1024 + cc] = f2b(v[j] + bv);
                } else {
                    // vT[b][col-2048][s], rows row0..row0+3 are consecutive s
                    const int b = row0 >> 12, s = row0 & 4095;
                    ushort4 h4;
                    h4.x = f2b(v[0] + bv); h4.y = f2b(v[1] + bv);
                    h4.z = f2b(v[2] + bv); h4.w = f2b(v[3] + bv);
                    *(ushort4*)((unsigned short*)C2 +
                                ((size_t)b * 1024 + (col - 2048)) * 4096 + s) = h4;
                }
            } else if (EPI == 1) {
#pragma unroll
                for (int j = 0; j < 4; ++j)
                    ((_Float16*)C0)[(size_t)z * cZ + (size_t)(row0 + j) * ldc + col] =
                        (_Float16)(v[j] * scale);
            } else if (EPI == 2) {
#pragma unroll
                for (int j = 0; j < 4; ++j)
                    ((unsigned short*)C0)[(size_t)z * cZ + (size_t)(row0 + j) * ldc + col] =
                        f2b(v[j]);
            } else {
#pragma unroll
                for (int j = 0; j < 4; ++j)
                    ((float*)C0)[(size_t)(row0 + j) * ldc + col] = v[j] + bias[col];
            }
        }
    }
}

// ---------------------------------------------------------------------------
// Row softmax in-place: reads 4096 f16, writes 4096 bf16 over the same bytes.
// ---------------------------------------------------------------------------
__global__ __launch_bounds__(256) void softmax_rows(unsigned short* __restrict__ sc)
{
    const size_t rowoff = (size_t)blockIdx.x * 4096;
    const int t = threadIdx.x;

    h8 a = *(const h8*)(sc + rowoff + t * 8);
    h8 b = *(const h8*)(sc + rowoff + 2048 + t * 8);
    float v[16];
#pragma unroll
    for (int i = 0; i < 8; ++i) { v[i] = (float)a[i]; v[8 + i] = (float)b[i]; }

    float mx = -1e30f;
#pragma unroll
    for (int i = 0; i < 16; ++i) mx = fmaxf(mx, v[i]);
#pragma unroll
    for (int o = 32; o > 0; o >>= 1) mx = fmaxf(mx, __shfl_xor(mx, o));
    __shared__ float redm[4];
    if ((t & 63) == 0) redm[t >> 6] = mx;
    __syncthreads();
    mx = fmaxf(fmaxf(redm[0], redm[1]), fmaxf(redm[2], redm[3]));

    float sum = 0.f;
#pragma unroll
    for (int i = 0; i < 16; ++i) { v[i] = expf(v[i] - mx); sum += v[i]; }
#pragma unroll
    for (int o = 32; o > 0; o >>= 1) sum += __shfl_xor(sum, o);
    __shared__ float reds[4];
    if ((t & 63) == 0) reds[t >> 6] = sum;
    __syncthreads();
    sum = reds[0] + reds[1] + reds[2] + reds[3];
    const float rs = 1.f / sum;

    u16x8 w0, w1;
#pragma unroll
    for (int i = 0; i < 8; ++i) {
        w0[i] = f2b(v[i] * rs);
        w1[i] = f2b(v[8 + i] * rs);
    }
    *(u16x8*)(sc + rowoff + t * 8) = w0;
    *(u16x8*)(sc + rowoff + 2048 + t * 8) = w1;
}

__global__ __launch_bounds__(256) void cast_bf16(
    const float* __restrict__ in, unsigned short* __restrict__ out, int n4)
{
    const int i = blockIdx.x * 256 + threadIdx.x;
    if (i < n4) {
        float4 f = ((const float4*)in)[i];
        ushort4 o;
        o.x = f2b(f.x); o.y = f2b(f.y); o.z = f2b(f.z); o.w = f2b(f.w);
        ((ushort4*)out)[i] = o;
    }
}

// ---------------------------------------------------------------------------
extern "C" void kernel_launch(void* const* d_in, const int* in_sizes, int n_in,
                              void* d_out, int out_size, void* d_ws, size_t ws_size,
                              hipStream_t stream)
{
    const float* x      = (const float*)d_in[0];   // [4,4096,1024]
    const float* qkv_w  = (const float*)d_in[1];   // [3072,1024]
    const float* qkv_b  = (const float*)d_in[2];   // [3072]
    const float* out_w  = (const float*)d_in[3];   // [1024,1024]
    const float* out_b  = (const float*)d_in[4];   // [1024]
    float* out = (float*)d_out;                    // [4,4096,1024] fp32

    unsigned short* W = (unsigned short*)d_ws;
    const size_t M16 = 16777216;   // one [4,4096,1024] bf16 tensor (ushorts)

    if (ws_size >= 236978176ull) {
        // ---- big mode: 226 MiB peak ----
        unsigned short* sc   = W;
        unsigned short* q    = sc + 67108864;
        unsigned short* kk   = q + M16;
        unsigned short* vT   = kk + M16;
        unsigned short* wo   = vT + M16;
        unsigned short* xb   = sc;            // transient, dead before sc write
        unsigned short* wqkv = sc + M16;      // transient
        unsigned short* ao   = q;             // q dead after scores GEMM

        cast_bf16<<<16384, 256, 0, stream>>>(x, xb, 4194304);
        cast_bf16<<<3072, 256, 0, stream>>>(qkv_w, wqkv, 786432);
        cast_bf16<<<1024, 256, 0, stream>>>(out_w, wo, 262144);

        gemm_nt<0, 0><<<12 * 64, 512, 0, stream>>>(
            xb, wqkv, 0, 0, 1024, 1024, 1024, qkv_b, q, kk, vT, 0, 0, 0.f, 12, 64);

        gemm_nt<1, 0><<<16 * 16 * 4, 512, 0, stream>>>(
            q, kk, 4194304, 4194304, 1024, 1024, 1024, nullptr,
            sc, nullptr, nullptr, 16777216, 4096, 0.03125f, 16, 16);

        softmax_rows<<<16384, 256, 0, stream>>>(sc);

        gemm_nt<2, 1><<<4 * 16 * 4, 512, 0, stream>>>(
            sc, vT, 16777216, 4194304, 4096, 4096, 4096, nullptr,
            ao, nullptr, nullptr, 4194304, 1024, 0.f, 4, 16);

        gemm_nt<3, 0><<<4 * 64, 512, 0, stream>>>(
            ao, wo, 0, 0, 1024, 1024, 1024, out_b,
            out, nullptr, nullptr, 0, 1024, 0.f, 4, 64);
    } else {
        // ---- small mode: 168 MiB peak, per-batch scores buffer ----
        unsigned short* sc   = W;
        unsigned short* q    = sc + M16;
        unsigned short* kk   = q + M16;
        unsigned short* vT   = kk + M16;
        unsigned short* ao   = vT + M16;
        unsigned short* wo   = ao + M16;
        unsigned short* wqkv = wo + 1048576;
        unsigned short* xb   = sc;

        cast_bf16<<<16384, 256, 0, stream>>>(x, xb, 4194304);
        cast_bf16<<<3072, 256, 0, stream>>>(qkv_w, wqkv, 786432);
        cast_bf16<<<1024, 256, 0, stream>>>(out_w, wo, 262144);

        gemm_nt<0, 0><<<12 * 64, 512, 0, stream>>>(
            xb, wqkv, 0, 0, 1024, 1024, 1024, qkv_b, q, kk, vT, 0, 0, 0.f, 12, 64);

        for (int z = 0; z < 4; ++z) {
            const size_t zo = (size_t)z * 4194304;
            gemm_nt<1, 0><<<16 * 16, 512, 0, stream>>>(
                q + zo, kk + zo, 0, 0, 1024, 1024, 1024, nullptr,
                sc, nullptr, nullptr, 0, 4096, 0.03125f, 16, 16);
            softmax_rows<<<4096, 256, 0, stream>>>(sc);
            gemm_nt<2, 1><<<4 * 16, 512, 0, stream>>>(
                sc, vT + zo, 0, 0, 4096, 4096, 4096, nullptr,
                ao + zo, nullptr, nullptr, 0, 1024, 0.f, 4, 16);
        }

        gemm_nt<3, 0><<<4 * 64, 512, 0, stream>>>(
            ao, wo, 0, 0, 1024, 1024, 1024, out_b,
            out, nullptr, nullptr, 0, 1024, 0.f, 4, 64);
    }
}

// Round 8
// 496.325 us; speedup vs baseline: 1.3673x; 1.3673x over previous
//
#include <hip/hip_runtime.h>
#include <hip/hip_bf16.h>

typedef __bf16 bf16x8 __attribute__((ext_vector_type(8)));
typedef float f32x4 __attribute__((ext_vector_type(4)));
typedef _Float16 h8 __attribute__((ext_vector_type(8)));
typedef unsigned short u16x8 __attribute__((ext_vector_type(8)));

__device__ inline unsigned short f2b(float x) {
    __hip_bfloat16 h = __float2bfloat16(x);
    return __builtin_bit_cast(unsigned short, h);
}

__device__ inline void gload16(const void* g, void* l) {
    __builtin_amdgcn_global_load_lds(
        (const __attribute__((address_space(1))) unsigned int*)g,
        (__attribute__((address_space(3))) unsigned int*)l, 16, 0, 0);
}

#define BAR  asm volatile("s_barrier" ::: "memory")
#define VMC(N) asm volatile("s_waitcnt vmcnt(" #N ")" ::: "memory")
#define LKM0 asm volatile("s_waitcnt lgkmcnt(0)" ::: "memory")

// reads for one quadrant's A operands (m rows MO, MO+1; both k-halves)
#define RD_A(BASE, MO)                                                \
    af[0][0] = *(const bf16x8*)((BASE) + (MO) * 1024 + aoff0);        \
    af[0][1] = *(const bf16x8*)((BASE) + (MO) * 1024 + aoff1);        \
    af[1][0] = *(const bf16x8*)((BASE) + ((MO) + 1) * 1024 + aoff0);  \
    af[1][1] = *(const bf16x8*)((BASE) + ((MO) + 1) * 1024 + aoff1);

#define RD_B(BASE)                                                    \
    _Pragma("unroll")                                                 \
    for (int n_ = 0; n_ < 4; ++n_) {                                  \
        bfr[n_][0] = *(const bf16x8*)((BASE) + n_ * 1024 + aoff0);    \
        bfr[n_][1] = *(const bf16x8*)((BASE) + n_ * 1024 + aoff1);    \
    }

// 16 MFMA: quadrant m in {MO, MO+1} x 4 n x 2 kk, static acc indices.
// Compiler inserts the lgkm waits before first af/bfr use (rule-#18-safe).
#define MFMA_Q(MO)                                                    \
    __builtin_amdgcn_s_setprio(1);                                    \
    _Pragma("unroll")                                                 \
    for (int kk_ = 0; kk_ < 2; ++kk_)                                 \
        _Pragma("unroll")                                             \
        for (int mi_ = 0; mi_ < 2; ++mi_)                             \
            _Pragma("unroll")                                         \
            for (int n_ = 0; n_ < 4; ++n_)                            \
                acc[(MO) + mi_][n_] =                                 \
                    __builtin_amdgcn_mfma_f32_16x16x32_bf16(          \
                        af[mi_][kk_], bfr[n_][kk_],                   \
                        acc[(MO) + mi_][n_], 0, 0, 0);                \
    __builtin_amdgcn_s_setprio(0);

// ---------------------------------------------------------------------------
// NT GEMM: C[M,N] = A[M,K] * B[N,K]^T (+bias), A/B bf16 K-contiguous.
// r6 structure (verified 442us / 46% MfmaUtil): 8-phase / 2-K-tile schedule,
// ONE barrier per phase, stage issued in the MFMA shadow. 256x256 tile,
// BK=64, 512 thr = 8 waves (2Mx4N), wave tile 128x64, mfma 16x16x32.
// LDS = 2 bufs x [A0|A1|B0|B1] x 16KiB = 128 KiB.
// Phase p: { 4 (or 12) ds_read; [seal vmcnt before BAR at p3/p7]; s_barrier;
//            stage 1 half-tile (2 gload_lds, post-barrier -> overlaps MFMA);
//            setprio(1); 16 MFMA; setprio(0) }
// AF32=1 (QKV only): A is fp32 (x read DIRECTLY, cast kernel eliminated).
// A-staging becomes reg-staged (T14 split): q0/q4 issue 8 global_load_dwordx4
// into regs (consumed 2 phases later -> HBM latency hidden under 2 MFMA
// clusters); q2/q6 convert with f2b (same RNE as the old cast kernel ->
// bit-identical numerics) and 4x ds_write_b128 to the SAME swizzled LDS
// slots. Ledger: the cvt's implicit vmcnt drains the reg-loads at q2/q6, so
// the q3/q7 VMC(2) seals keep their r6 meaning (B(tile) landed, newest B
// half flying, never 0 mid-loop). ds_writes retired via LKM0 (memory
// clobber) before the seal barrier; first cross-wave reads of the buffer are
// >=1 barrier later. Prologue: A regs issued first (wait = vmcnt(8), all 8 B
// gloads may fly), then VMC(4)+LKM0+BAR — same ledger as steady state.
// Swizzle (0-conflict, r2-verified): 16B granule g' = g ^ (row&7); source
// pre-swizzled within the row's 128B line, dest linear, ds_read applies the
// same involution.
// EPI: 0 = QKV router (bias, q/k normal, v transposed), 1 = f16*scale (scores),
//      2 = bf16 (PV->ao), 3 = f32+bias (final out)
// ---------------------------------------------------------------------------
template<int EPI, int SWZ, int AF32 = 0>
__global__ __launch_bounds__(512, 2) void gemm_nt(
    const void* __restrict__ Av, const unsigned short* __restrict__ B,
    long aZ, long bZ, int lda, int ldb, int K,
    const float* __restrict__ bias,
    void* __restrict__ C0, void* __restrict__ C1, void* __restrict__ C2,
    long cZ, int ldc, float scale, int gx, int gy)
{
    __shared__ __attribute__((aligned(16))) unsigned short lds[2][4][8192];

    int wgid;
    if (SWZ) {
        const int nwg = (int)gridDim.x;
        const int bid = (int)blockIdx.x;
        const int qch = nwg >> 3, rch = nwg & 7;
        const int xcd = bid & 7, idx = bid >> 3;
        wgid = (xcd < rch ? xcd * (qch + 1)
                          : rch * (qch + 1) + (xcd - rch) * qch) + idx;
    } else {
        wgid = (int)blockIdx.x;
    }
    const int bx = wgid % gx;
    const int rem = wgid / gx;
    const int by = rem % gy;
    const int z = rem / gy;

    const int t = threadIdx.x;
    const int lane = t & 63, wid = t >> 6;
    const int wr = wid >> 2, wc = wid & 3;           // 2 x 4 wave grid
    const int tileM = by * 256, tileN = bx * 256;
    const unsigned short* A = (const unsigned short*)Av + (size_t)z * aZ;
    const float* Af = (const float*)Av + (size_t)z * aZ;
    B += (size_t)z * bZ;

    f32x4 acc[8][4] = {};

    // ---- read geometry: frag element k = kk*32 + qw*8 (qw = lane>>4);
    // granule g = kk*4+qw; physical g^(row&7), row&7 == lane&7.
    const int l4 = lane & 15, qw = lane >> 4, sw = lane & 7;
    const int aoff0 = l4 * 64 + ((qw ^ sw) << 3);
    const int aoff1 = l4 * 64 + (((4 | qw) ^ sw) << 3);

    // per-wave LDS read bases (compile-time buffer indices)
    const unsigned short* aB0 = &lds[0][wr][0];
    const unsigned short* aB1 = &lds[1][wr][0];
    const unsigned short* bB0 = &lds[0][2 + (wc >> 1)][0] + (wc & 1) * 4096;
    const unsigned short* bB1 = &lds[1][2 + (wc >> 1)][0] + (wc & 1) * 4096;

    // staging dest bases
    char* const ldsA[2] = {(char*)&lds[0][0][0], (char*)&lds[1][0][0]};
    char* const ldsB[2] = {(char*)&lds[0][2][0], (char*)&lds[1][2][0]};

    // ---- staging geometry: half-tile = 128 rows x 64 K, 2 chunks/thread.
    // row = t>>3 (+64), phys granule = t&7, src granule = (t ^ (t>>3)) & 7.
    const int srow = t >> 3;
    const int sg = ((t ^ (t >> 3)) & 7) << 3;
    const unsigned short* Asrc0 = A + (size_t)(tileM + srow) * lda + sg;
    const unsigned short* Asrc1 = Asrc0 + (size_t)128 * lda;
    const unsigned short* Bsrc0 = B + (size_t)(tileN + srow) * ldb + sg;
    const unsigned short* Bsrc1 = Bsrc0 + (size_t)128 * ldb;
    const float* fA0 = Af + (size_t)(tileM + srow) * lda + sg;
    const float* fA1 = fA0 + (size_t)128 * lda;

    auto stageA = [&](char* Lb, int koff, int h) {
        char* dst = Lb + h * 16384 + wid * 1024;
        const unsigned short* s = (h ? Asrc1 : Asrc0) + koff;
        gload16(s, dst);
        gload16(s + (size_t)64 * lda, dst + 8192);
    };
    auto stageB = [&](char* Lb, int koff, int h) {
        char* dst = Lb + h * 16384 + wid * 1024;
        const unsigned short* s = (h ? Bsrc1 : Bsrc0) + koff;
        gload16(s, dst);
        gload16(s + (size_t)64 * ldb, dst + 8192);
    };

    // fp32 A reg-staging (AF32 path): full A-tile (4 chunks of 8 elems)
    float4 ar0, ar1, ar2, ar3, ar4, ar5, ar6, ar7;
    auto aregload = [&](int koff) {
        const float* s0 = fA0 + koff;
        const float* s1 = fA0 + (size_t)64 * lda + koff;
        const float* s2 = fA1 + koff;
        const float* s3 = fA1 + (size_t)64 * lda + koff;
        ar0 = *(const float4*)s0; ar1 = *(const float4*)(s0 + 4);
        ar2 = *(const float4*)s1; ar3 = *(const float4*)(s1 + 4);
        ar4 = *(const float4*)s2; ar5 = *(const float4*)(s2 + 4);
        ar6 = *(const float4*)s3; ar7 = *(const float4*)(s3 + 4);
    };
    auto awrite = [&](char* Lb) {
        u16x8 w0, w1, w2, w3;
        w0[0]=f2b(ar0.x); w0[1]=f2b(ar0.y); w0[2]=f2b(ar0.z); w0[3]=f2b(ar0.w);
        w0[4]=f2b(ar1.x); w0[5]=f2b(ar1.y); w0[6]=f2b(ar1.z); w0[7]=f2b(ar1.w);
        w1[0]=f2b(ar2.x); w1[1]=f2b(ar2.y); w1[2]=f2b(ar2.z); w1[3]=f2b(ar2.w);
        w1[4]=f2b(ar3.x); w1[5]=f2b(ar3.y); w1[6]=f2b(ar3.z); w1[7]=f2b(ar3.w);
        w2[0]=f2b(ar4.x); w2[1]=f2b(ar4.y); w2[2]=f2b(ar4.z); w2[3]=f2b(ar4.w);
        w2[4]=f2b(ar5.x); w2[5]=f2b(ar5.y); w2[6]=f2b(ar5.z); w2[7]=f2b(ar5.w);
        w3[0]=f2b(ar6.x); w3[1]=f2b(ar6.y); w3[2]=f2b(ar6.z); w3[3]=f2b(ar6.w);
        w3[4]=f2b(ar7.x); w3[5]=f2b(ar7.y); w3[6]=f2b(ar7.z); w3[7]=f2b(ar7.w);
        *(u16x8*)(Lb + t * 16)         = w0;
        *(u16x8*)(Lb + 8192 + t * 16)  = w1;
        *(u16x8*)(Lb + 16384 + t * 16) = w2;
        *(u16x8*)(Lb + 24576 + t * 16) = w3;
    };

    const int NT = K >> 6;            // BK=64; K % 128 == 0 here -> NT even
    const int NI = NT >> 1;

    // prologue: tile0 fully + B halves of tile1; seal tile0 (B(1) flies).
    if constexpr (AF32) {
        aregload(0);                               // 8 reg-loads (oldest)
        stageB(ldsB[0], 0, 0); stageB(ldsB[0], 0, 1);
        stageB(ldsB[1], 64, 0); stageB(ldsB[1], 64, 1);
        awrite(ldsA[0]);                           // waits vmcnt(8): B flies
        VMC(4);                                    // B(0) landed
        LKM0;                                      // A(0) writes retired
    } else {
        stageA(ldsA[0], 0, 0); stageA(ldsA[0], 0, 1);
        stageB(ldsB[0], 0, 0); stageB(ldsB[0], 0, 1);
        stageB(ldsB[1], 64, 0); stageB(ldsB[1], 64, 1);
        VMC(4);
    }
    BAR;

    bf16x8 af[2][2], bfr[4][2];

#pragma unroll 1
    for (int i = 0; i < NI - 1; ++i) {
        const int kb = i * 128;
        const int ko = kb + 64, ke2 = kb + 128, ko2 = kb + 192;

        // p0
        RD_B(bB0); RD_A(aB0, 0);
        BAR;
        if constexpr (AF32) aregload(ko); else stageA(ldsA[1], ko, 0);
        MFMA_Q(0)
        // p1
        RD_A(aB0, 2);
        BAR;
        if constexpr (!AF32) stageA(ldsA[1], ko, 1);
        MFMA_Q(2)
        // p2
        RD_A(aB0, 4);
        BAR; stageB(ldsB[0], ke2, 0);
        if constexpr (AF32) awrite(ldsA[1]);   // cvt waits regs; writes A(o)
        MFMA_Q(4)
        // p3: seal tile o (newest half B0(e+2) may fly)
        RD_A(aB0, 6);
        VMC(2);
        if constexpr (AF32) LKM0;              // A(o) ds_writes retired
        BAR; stageB(ldsB[0], ke2, 1);
        MFMA_Q(6)
        // p4
        RD_B(bB1); RD_A(aB1, 0);
        BAR;
        if constexpr (AF32) aregload(ke2); else stageA(ldsA[0], ke2, 0);
        MFMA_Q(0)
        // p5
        RD_A(aB1, 2);
        BAR;
        if constexpr (!AF32) stageA(ldsA[0], ke2, 1);
        MFMA_Q(2)
        // p6
        RD_A(aB1, 4);
        BAR; stageB(ldsB[1], ko2, 0);
        if constexpr (AF32) awrite(ldsA[0]);   // writes A(e+2)
        MFMA_Q(4)
        // p7: seal tile e+2 (newest half B0(o+2) may fly)
        RD_A(aB1, 6);
        VMC(2);
        if constexpr (AF32) LKM0;              // A(e+2) ds_writes retired
        BAR; stageB(ldsB[1], ko2, 1);
        MFMA_Q(6)
    }

    {   // ---- peeled final iteration (no future stages)
        const int ko = (NI - 1) * 128 + 64;
        RD_B(bB0); RD_A(aB0, 0);
        BAR;
        if constexpr (AF32) aregload(ko); else stageA(ldsA[1], ko, 0);
        MFMA_Q(0)
        RD_A(aB0, 2);
        BAR;
        if constexpr (!AF32) stageA(ldsA[1], ko, 1);
        MFMA_Q(2)
        RD_A(aB0, 4);
        BAR;
        if constexpr (AF32) awrite(ldsA[1]);
        MFMA_Q(4)
        RD_A(aB0, 6);
        VMC(0);
        if constexpr (AF32) LKM0;
        BAR;
        MFMA_Q(6)
        RD_B(bB1); RD_A(aB1, 0);
        BAR;
        MFMA_Q(0)
        RD_A(aB1, 2);
        BAR;
        MFMA_Q(2)
        RD_A(aB1, 4);
        BAR;
        MFMA_Q(4)
        RD_A(aB1, 6);
        BAR;
        MFMA_Q(6)
    }

    // epilogue: C/D layout col = lane&15, row = (lane>>4)*4 + j  [m89-verified]
    const int lr = lane >> 4, lc = lane & 15;
#pragma unroll
    for (int m = 0; m < 8; ++m) {
#pragma unroll
        for (int n = 0; n < 4; ++n) {
            f32x4 v = acc[m][n];
            const int col = tileN + wc * 64 + n * 16 + lc;
            const int row0 = tileM + wr * 128 + m * 16 + lr * 4;
            if (EPI == 0) {
                const float bv = bias[col];
                if (col < 2048) {
                    unsigned short* dst = (col < 1024) ? (unsigned short*)C0
                                                       : (unsigned short*)C1;
                    const int cc = col & 1023;
#pragma unroll
                    for (int j = 0; j < 4; ++j)
                        dst[(size_t)(row0 + j) * 1024 + cc] = f2b(v[j] + bv);
                } else {
                    // vT[b][col-2048][s], rows row0..row0+3 are consecutive s
                    const int b = row0 >> 12, s = row0 & 4095;
                    ushort4 h4;
                    h4.x = f2b(v[0] + bv); h4.y = f2b(v[1] + bv);
                    h4.z = f2b(v[2] + bv); h4.w = f2b(v[3] + bv);
                    *(ushort4*)((unsigned short*)C2 +
                                ((size_t)b * 1024 + (col - 2048)) * 4096 + s) = h4;
                }
            } else if (EPI == 1) {
#pragma unroll
                for (int j = 0; j < 4; ++j)
                    ((_Float16*)C0)[(size_t)z * cZ + (size_t)(row0 + j) * ldc + col] =
                        (_Float16)(v[j] * scale);
            } else if (EPI == 2) {
#pragma unroll
                for (int j = 0; j < 4; ++j)
                    ((unsigned short*)C0)[(size_t)z * cZ + (size_t)(row0 + j) * ldc + col] =
                        f2b(v[j]);
            } else {
#pragma unroll
                for (int j = 0; j < 4; ++j)
                    ((float*)C0)[(size_t)(row0 + j) * ldc + col] = v[j] + bias[col];
            }
        }
    }
}

// ---------------------------------------------------------------------------
// Row softmax in-place: reads 4096 f16, writes 4096 bf16 over the same bytes.
// ---------------------------------------------------------------------------
__global__ __launch_bounds__(256) void softmax_rows(unsigned short* __restrict__ sc)
{
    const size_t rowoff = (size_t)blockIdx.x * 4096;
    const int t = threadIdx.x;

    h8 a = *(const h8*)(sc + rowoff + t * 8);
    h8 b = *(const h8*)(sc + rowoff + 2048 + t * 8);
    float v[16];
#pragma unroll
    for (int i = 0; i < 8; ++i) { v[i] = (float)a[i]; v[8 + i] = (float)b[i]; }

    float mx = -1e30f;
#pragma unroll
    for (int i = 0; i < 16; ++i) mx = fmaxf(mx, v[i]);
#pragma unroll
    for (int o = 32; o > 0; o >>= 1) mx = fmaxf(mx, __shfl_xor(mx, o));
    __shared__ float redm[4];
    if ((t & 63) == 0) redm[t >> 6] = mx;
    __syncthreads();
    mx = fmaxf(fmaxf(redm[0], redm[1]), fmaxf(redm[2], redm[3]));

    float sum = 0.f;
#pragma unroll
    for (int i = 0; i < 16; ++i) { v[i] = expf(v[i] - mx); sum += v[i]; }
#pragma unroll
    for (int o = 32; o > 0; o >>= 1) sum += __shfl_xor(sum, o);
    __shared__ float reds[4];
    if ((t & 63) == 0) reds[t >> 6] = sum;
    __syncthreads();
    sum = reds[0] + reds[1] + reds[2] + reds[3];
    const float rs = 1.f / sum;

    u16x8 w0, w1;
#pragma unroll
    for (int i = 0; i < 8; ++i) {
        w0[i] = f2b(v[i] * rs);
        w1[i] = f2b(v[8 + i] * rs);
    }
    *(u16x8*)(sc + rowoff + t * 8) = w0;
    *(u16x8*)(sc + rowoff + 2048 + t * 8) = w1;
}

__global__ __launch_bounds__(256) void cast_bf16(
    const float* __restrict__ in, unsigned short* __restrict__ out, int n4)
{
    const int i = blockIdx.x * 256 + threadIdx.x;
    if (i < n4) {
        float4 f = ((const float4*)in)[i];
        ushort4 o;
        o.x = f2b(f.x); o.y = f2b(f.y); o.z = f2b(f.z); o.w = f2b(f.w);
        ((ushort4*)out)[i] = o;
    }
}

// ---------------------------------------------------------------------------
extern "C" void kernel_launch(void* const* d_in, const int* in_sizes, int n_in,
                              void* d_out, int out_size, void* d_ws, size_t ws_size,
                              hipStream_t stream)
{
    const float* x      = (const float*)d_in[0];   // [4,4096,1024]
    const float* qkv_w  = (const float*)d_in[1];   // [3072,1024]
    const float* qkv_b  = (const float*)d_in[2];   // [3072]
    const float* out_w  = (const float*)d_in[3];   // [1024,1024]
    const float* out_b  = (const float*)d_in[4];   // [1024]
    float* out = (float*)d_out;                    // [4,4096,1024] fp32

    unsigned short* W = (unsigned short*)d_ws;
    const size_t M16 = 16777216;   // one [4,4096,1024] bf16 tensor (ushorts)

    if (ws_size >= 236978176ull) {
        // ---- big mode: 226 MiB peak ----
        unsigned short* sc   = W;
        unsigned short* q    = sc + 67108864;
        unsigned short* kk   = q + M16;
        unsigned short* vT   = kk + M16;
        unsigned short* wo   = vT + M16;
        unsigned short* wqkv = sc + M16;      // transient, dead before sc write
        unsigned short* ao   = q;             // q dead after scores GEMM

        cast_bf16<<<3072, 256, 0, stream>>>(qkv_w, wqkv, 786432);
        cast_bf16<<<1024, 256, 0, stream>>>(out_w, wo, 262144);

        // QKV: A = x fp32 directly (AF32=1), cast fused into staging
        gemm_nt<0, 0, 1><<<12 * 64, 512, 0, stream>>>(
            x, wqkv, 0, 0, 1024, 1024, 1024, qkv_b, q, kk, vT, 0, 0, 0.f, 12, 64);

        gemm_nt<1, 0><<<16 * 16 * 4, 512, 0, stream>>>(
            q, kk, 4194304, 4194304, 1024, 1024, 1024, nullptr,
            sc, nullptr, nullptr, 16777216, 4096, 0.03125f, 16, 16);

        softmax_rows<<<16384, 256, 0, stream>>>(sc);

        gemm_nt<2, 1><<<4 * 16 * 4, 512, 0, stream>>>(
            sc, vT, 16777216, 4194304, 4096, 4096, 4096, nullptr,
            ao, nullptr, nullptr, 4194304, 1024, 0.f, 4, 16);

        gemm_nt<3, 0><<<4 * 64, 512, 0, stream>>>(
            ao, wo, 0, 0, 1024, 1024, 1024, out_b,
            out, nullptr, nullptr, 0, 1024, 0.f, 4, 64);
    } else {
        // ---- small mode: per-batch scores buffer ----
        unsigned short* sc   = W;
        unsigned short* q    = sc + M16;
        unsigned short* kk   = q + M16;
        unsigned short* vT   = kk + M16;
        unsigned short* ao   = vT + M16;
        unsigned short* wo   = ao + M16;
        unsigned short* wqkv = wo + 1048576;

        cast_bf16<<<3072, 256, 0, stream>>>(qkv_w, wqkv, 786432);
        cast_bf16<<<1024, 256, 0, stream>>>(out_w, wo, 262144);

        gemm_nt<0, 0, 1><<<12 * 64, 512, 0, stream>>>(
            x, wqkv, 0, 0, 1024, 1024, 1024, qkv_b, q, kk, vT, 0, 0, 0.f, 12, 64);

        for (int z = 0; z < 4; ++z) {
            const size_t zo = (size_t)z * 4194304;
            gemm_nt<1, 0><<<16 * 16, 512, 0, stream>>>(
                q + zo, kk + zo, 0, 0, 1024, 1024, 1024, nullptr,
                sc, nullptr, nullptr, 0, 4096, 0.03125f, 16, 16);
            softmax_rows<<<4096, 256, 0, stream>>>(sc);
            gemm_nt<2, 1><<<4 * 16, 512, 0, stream>>>(
                sc, vT + zo, 0, 0, 4096, 4096, 4096, nullptr,
                ao + zo, nullptr, nullptr, 0, 1024, 0.f, 4, 16);
        }

        gemm_nt<3, 0><<<4 * 64, 512, 0, stream>>>(
            ao, wo, 0, 0, 1024, 1024, 1024, out_b,
            out, nullptr, nullptr, 0, 1024, 0.f, 4, 64);
    }
}

// Round 9
// 463.567 us; speedup vs baseline: 1.4639x; 1.0707x over previous
//
#include <hip/hip_runtime.h>
#include <hip/hip_bf16.h>

typedef __bf16 bf16x8 __attribute__((ext_vector_type(8)));
typedef float f32x4 __attribute__((ext_vector_type(4)));
typedef _Float16 h8 __attribute__((ext_vector_type(8)));
typedef unsigned short u16x8 __attribute__((ext_vector_type(8)));

__device__ inline unsigned short f2b(float x) {
    __hip_bfloat16 h = __float2bfloat16(x);
    return __builtin_bit_cast(unsigned short, h);
}

__device__ inline void gload16(const void* g, void* l) {
    __builtin_amdgcn_global_load_lds(
        (const __attribute__((address_space(1))) unsigned int*)g,
        (__attribute__((address_space(3))) unsigned int*)l, 16, 0, 0);
}

#define BAR  asm volatile("s_barrier" ::: "memory")
#define VMC(N) asm volatile("s_waitcnt vmcnt(" #N ")" ::: "memory")

// reads for one quadrant's A operands (m rows MO, MO+1; both k-halves)
#define RD_A(BASE, MO)                                                \
    af[0][0] = *(const bf16x8*)((BASE) + (MO) * 1024 + aoff0);        \
    af[0][1] = *(const bf16x8*)((BASE) + (MO) * 1024 + aoff1);        \
    af[1][0] = *(const bf16x8*)((BASE) + ((MO) + 1) * 1024 + aoff0);  \
    af[1][1] = *(const bf16x8*)((BASE) + ((MO) + 1) * 1024 + aoff1);

#define RD_B(BASE)                                                    \
    _Pragma("unroll")                                                 \
    for (int n_ = 0; n_ < 4; ++n_) {                                  \
        bfr[n_][0] = *(const bf16x8*)((BASE) + n_ * 1024 + aoff0);    \
        bfr[n_][1] = *(const bf16x8*)((BASE) + n_ * 1024 + aoff1);    \
    }

// 16 MFMA: quadrant m in {MO, MO+1} x 4 n x 2 kk, static acc indices.
// Compiler inserts the lgkm waits before first af/bfr use (rule-#18-safe).
#define MFMA_Q(MO)                                                    \
    __builtin_amdgcn_s_setprio(1);                                    \
    _Pragma("unroll")                                                 \
    for (int kk_ = 0; kk_ < 2; ++kk_)                                 \
        _Pragma("unroll")                                             \
        for (int mi_ = 0; mi_ < 2; ++mi_)                             \
            _Pragma("unroll")                                         \
            for (int n_ = 0; n_ < 4; ++n_)                            \
                acc[(MO) + mi_][n_] =                                 \
                    __builtin_amdgcn_mfma_f32_16x16x32_bf16(          \
                        af[mi_][kk_], bfr[n_][kk_],                   \
                        acc[(MO) + mi_][n_], 0, 0, 0);                \
    __builtin_amdgcn_s_setprio(0);

// ---------------------------------------------------------------------------
// NT GEMM: C[M,N] = A[M,K] * B[N,K]^T (+bias), A/B bf16 K-contiguous.
// r6 structure + RING-3 A BUFFER (deep prefetch, uniform VMC(6) seals).
// 256x256 tile, BK=64, 512 thr = 8 waves (2Mx4N), wave tile 128x64,
// mfma 16x16x32. LDS = A ring-3 x 32KiB + B ring-2 x 32KiB = 160 KiB
// (gfx950 max; AITER attn precedent). VGPR unchanged (all buffer indices
// compile-time via period-3 unroll; NI in {8,32}, both == 2 mod 3).
// Iteration (tiles e=2j -> bufA[(2j)%3], o -> bufA[(2j+1)%3]); 8 phases:
//   p: { ds_read quadrant (+8 B at p0/p4); [VMC(6) at p3/p7]; s_barrier;
//        stage 1 half-tile (2 gload_lds, in MFMA shadow); 16 MFMA }
// Stage plan: p0/p1: A(e+2) -> bufA[(BE+2)%3] (7-phase lead to its read);
//             p2/p3: B(e+2) -> ldsB[0];  p4/p5: A(o+2) -> bufA[BE] (freed
//             at p3, 8-phase lead);       p6/p7: B(o+2) -> ldsB[1].
// Seals: p3 VMC(6) guarantees A(o)+B(o) landed (issued >=4 phases ago,
// never stalls), leaves this iter's 6 newest loads flying; p7 VMC(6)
// guarantees A(e+2)+B(e+2) landed (>=4 phases old). 3 half-tiles always in
// flight = m201's counted-vmcnt depth. Never 0 mid-loop (T4).
// Hazards: every LDS overwrite lands >=1 barrier after its region's reads
// drained (reads consumed by same-phase MFMA before next barrier);
// seal-before-barrier makes per-wave vmcnt collective.
// Swizzle (0-conflict, r2-verified): 16B granule g' = g ^ (row&7); source
// pre-swizzled within the row's 128B line, gload_lds dest linear, ds_read
// applies the same involution.
// EPI: 0 = QKV router (bias, q/k normal, v transposed), 1 = f16*scale (scores),
//      2 = bf16 (PV->ao), 3 = f32+bias (final out)
// ---------------------------------------------------------------------------
template<int EPI, int SWZ>
__global__ __launch_bounds__(512, 2) void gemm_nt(
    const unsigned short* __restrict__ A, const unsigned short* __restrict__ B,
    long aZ, long bZ, int lda, int ldb, int K,
    const float* __restrict__ bias,
    void* __restrict__ C0, void* __restrict__ C1, void* __restrict__ C2,
    long cZ, int ldc, float scale, int gx, int gy)
{
    __shared__ __attribute__((aligned(16))) unsigned short ldsA[3][16384];
    __shared__ __attribute__((aligned(16))) unsigned short ldsB[2][16384];

    int wgid;
    if (SWZ) {
        const int nwg = (int)gridDim.x;
        const int bid = (int)blockIdx.x;
        const int qch = nwg >> 3, rch = nwg & 7;
        const int xcd = bid & 7, idx = bid >> 3;
        wgid = (xcd < rch ? xcd * (qch + 1)
                          : rch * (qch + 1) + (xcd - rch) * qch) + idx;
    } else {
        wgid = (int)blockIdx.x;
    }
    const int bx = wgid % gx;
    const int rem = wgid / gx;
    const int by = rem % gy;
    const int z = rem / gy;

    const int t = threadIdx.x;
    const int lane = t & 63, wid = t >> 6;
    const int wr = wid >> 2, wc = wid & 3;           // 2 x 4 wave grid
    const int tileM = by * 256, tileN = bx * 256;
    A += (size_t)z * aZ;
    B += (size_t)z * bZ;

    f32x4 acc[8][4] = {};

    // ---- read geometry: frag element k = kk*32 + qw*8 (qw = lane>>4);
    // granule g = kk*4+qw; physical g^(row&7), row&7 == lane&7.
    const int l4 = lane & 15, qw = lane >> 4, sw = lane & 7;
    const int aoff0 = l4 * 64 + ((qw ^ sw) << 3);
    const int aoff1 = l4 * 64 + (((4 | qw) ^ sw) << 3);

    // B read bases (compile-time): wave wc owns rows wc*64..wc*64+63
    const unsigned short* bB0 = &ldsB[0][0] + wc * 4096;
    const unsigned short* bB1 = &ldsB[1][0] + wc * 4096;

    // ---- staging geometry: half-tile = 128 rows x 64 K, 2 gload16/thread.
    // row = t>>3 (+64), phys granule = t&7, src granule = (t ^ (t>>3)) & 7.
    const int srow = t >> 3;
    const int sg = ((t ^ (t >> 3)) & 7) << 3;
    const unsigned short* Asrc0 = A + (size_t)(tileM + srow) * lda + sg;
    const unsigned short* Asrc1 = Asrc0 + (size_t)128 * lda;
    const unsigned short* Bsrc0 = B + (size_t)(tileN + srow) * ldb + sg;
    const unsigned short* Bsrc1 = Bsrc0 + (size_t)128 * ldb;

    auto stageAh = [&](int buf, int koff, int h) {
        char* dst = (char*)&ldsA[buf][0] + h * 16384 + wid * 1024;
        const unsigned short* s = (h ? Asrc1 : Asrc0) + koff;
        gload16(s, dst);
        gload16(s + (size_t)64 * lda, dst + 8192);
    };
    auto stageBh = [&](int buf, int koff, int h) {
        char* dst = (char*)&ldsB[buf][0] + h * 16384 + wid * 1024;
        const unsigned short* s = (h ? Bsrc1 : Bsrc0) + koff;
        gload16(s, dst);
        gload16(s + (size_t)64 * ldb, dst + 8192);
    };

    const int NT = K >> 6;            // BK=64; K in {1024,4096} -> NT {16,64}
    const int NI = NT >> 1;           // NI in {8,32}; NI % 3 == 2

    // prologue: A(0)->buf0, B(0), A(1)->buf1, B(1); seal tile0, leave 8 flying
    stageAh(0, 0, 0); stageAh(0, 0, 1);
    stageBh(0, 0, 0); stageBh(0, 0, 1);
    stageAh(1, 64, 0); stageAh(1, 64, 1);
    stageBh(1, 64, 0); stageBh(1, 64, 1);
    VMC(8);
    BAR;

    bf16x8 af[2][2], bfr[4][2];
    int kb = 0;

#define ITER(BE_, BN_, BS_)                                           \
    {                                                                 \
        const unsigned short* aE = &ldsA[BE_][0] + wr * 8192;         \
        const unsigned short* aO = &ldsA[BN_][0] + wr * 8192;         \
        const int ke2 = kb + 128, ko2 = kb + 192;                     \
        RD_B(bB0); RD_A(aE, 0);                                       \
        BAR; stageAh(BS_, ke2, 0); MFMA_Q(0)                          \
        RD_A(aE, 2);                                                  \
        BAR; stageAh(BS_, ke2, 1); MFMA_Q(2)                          \
        RD_A(aE, 4);                                                  \
        BAR; stageBh(0, ke2, 0); MFMA_Q(4)                            \
        RD_A(aE, 6); VMC(6);                                          \
        BAR; stageBh(0, ke2, 1); MFMA_Q(6)                            \
        RD_B(bB1); RD_A(aO, 0);                                       \
        BAR; stageAh(BE_, ko2, 0); MFMA_Q(0)                          \
        RD_A(aO, 2);                                                  \
        BAR; stageAh(BE_, ko2, 1); MFMA_Q(2)                          \
        RD_A(aO, 4);                                                  \
        BAR; stageBh(1, ko2, 0); MFMA_Q(4)                            \
        RD_A(aO, 6); VMC(6);                                          \
        BAR; stageBh(1, ko2, 1); MFMA_Q(6)                            \
        kb += 128;                                                    \
    }

    const int n3 = (NI - 2) / 3;      // NI=8 -> 2, NI=32 -> 10
#pragma unroll 1
    for (int i3 = 0; i3 < n3; ++i3) {
        ITER(0, 1, 2)
        ITER(2, 0, 1)
        ITER(1, 2, 0)
    }
    ITER(0, 1, 2)                     // j = NI-2 (be=0); stages last tiles

    {   // ---- peeled final iteration: be=2 -> aE=buf2, aO=buf0; no stages
        const unsigned short* aE = &ldsA[2][0] + wr * 8192;
        const unsigned short* aO = &ldsA[0][0] + wr * 8192;
        RD_B(bB0); RD_A(aE, 0);
        BAR; MFMA_Q(0)
        RD_A(aE, 2);
        BAR; MFMA_Q(2)
        RD_A(aE, 4);
        BAR; MFMA_Q(4)
        RD_A(aE, 6); VMC(0);
        BAR; MFMA_Q(6)
        RD_B(bB1); RD_A(aO, 0);
        BAR; MFMA_Q(0)
        RD_A(aO, 2);
        BAR; MFMA_Q(2)
        RD_A(aO, 4);
        BAR; MFMA_Q(4)
        RD_A(aO, 6);
        BAR; MFMA_Q(6)
    }
#undef ITER

    // epilogue: C/D layout col = lane&15, row = (lane>>4)*4 + j  [m89-verified]
    const int lr = lane >> 4, lc = lane & 15;
#pragma unroll
    for (int m = 0; m < 8; ++m) {
#pragma unroll
        for (int n = 0; n < 4; ++n) {
            f32x4 v = acc[m][n];
            const int col = tileN + wc * 64 + n * 16 + lc;
            const int row0 = tileM + wr * 128 + m * 16 + lr * 4;
            if (EPI == 0) {
                const float bv = bias[col];
                if (col < 2048) {
                    unsigned short* dst = (col < 1024) ? (unsigned short*)C0
                                                       : (unsigned short*)C1;
                    const int cc = col & 1023;
#pragma unroll
                    for (int j = 0; j < 4; ++j)
                        dst[(size_t)(row0 + j) * 1024 + cc] = f2b(v[j] + bv);
                } else {
                    // vT[b][col-2048][s], rows row0..row0+3 are consecutive s
                    const int b = row0 >> 12, s = row0 & 4095;
                    ushort4 h4;
                    h4.x = f2b(v[0] + bv); h4.y = f2b(v[1] + bv);
                    h4.z = f2b(v[2] + bv); h4.w = f2b(v[3] + bv);
                    *(ushort4*)((unsigned short*)C2 +
                                ((size_t)b * 1024 + (col - 2048)) * 4096 + s) = h4;
                }
            } else if (EPI == 1) {
#pragma unroll
                for (int j = 0; j < 4; ++j)
                    ((_Float16*)C0)[(size_t)z * cZ + (size_t)(row0 + j) * ldc + col] =
                        (_Float16)(v[j] * scale);
            } else if (EPI == 2) {
#pragma unroll
                for (int j = 0; j < 4; ++j)
                    ((unsigned short*)C0)[(size_t)z * cZ + (size_t)(row0 + j) * ldc + col] =
                        f2b(v[j]);
            } else {
#pragma unroll
                for (int j = 0; j < 4; ++j)
                    ((float*)C0)[(size_t)(row0 + j) * ldc + col] = v[j] + bias[col];
            }
        }
    }
}

// ---------------------------------------------------------------------------
// Row softmax in-place: reads 4096 f16, writes 4096 bf16 over the same bytes.
// ---------------------------------------------------------------------------
__global__ __launch_bounds__(256) void softmax_rows(unsigned short* __restrict__ sc)
{
    const size_t rowoff = (size_t)blockIdx.x * 4096;
    const int t = threadIdx.x;

    h8 a = *(const h8*)(sc + rowoff + t * 8);
    h8 b = *(const h8*)(sc + rowoff + 2048 + t * 8);
    float v[16];
#pragma unroll
    for (int i = 0; i < 8; ++i) { v[i] = (float)a[i]; v[8 + i] = (float)b[i]; }

    float mx = -1e30f;
#pragma unroll
    for (int i = 0; i < 16; ++i) mx = fmaxf(mx, v[i]);
#pragma unroll
    for (int o = 32; o > 0; o >>= 1) mx = fmaxf(mx, __shfl_xor(mx, o));
    __shared__ float redm[4];
    if ((t & 63) == 0) redm[t >> 6] = mx;
    __syncthreads();
    mx = fmaxf(fmaxf(redm[0], redm[1]), fmaxf(redm[2], redm[3]));

    float sum = 0.f;
#pragma unroll
    for (int i = 0; i < 16; ++i) { v[i] = expf(v[i] - mx); sum += v[i]; }
#pragma unroll
    for (int o = 32; o > 0; o >>= 1) sum += __shfl_xor(sum, o);
    __shared__ float reds[4];
    if ((t & 63) == 0) reds[t >> 6] = sum;
    __syncthreads();
    sum = reds[0] + reds[1] + reds[2] + reds[3];
    const float rs = 1.f / sum;

    u16x8 w0, w1;
#pragma unroll
    for (int i = 0; i < 8; ++i) {
        w0[i] = f2b(v[i] * rs);
        w1[i] = f2b(v[8 + i] * rs);
    }
    *(u16x8*)(sc + rowoff + t * 8) = w0;
    *(u16x8*)(sc + rowoff + 2048 + t * 8) = w1;
}

__global__ __launch_bounds__(256) void cast_bf16(
    const float* __restrict__ in, unsigned short* __restrict__ out, int n4)
{
    const int i = blockIdx.x * 256 + threadIdx.x;
    if (i < n4) {
        float4 f = ((const float4*)in)[i];
        ushort4 o;
        o.x = f2b(f.x); o.y = f2b(f.y); o.z = f2b(f.z); o.w = f2b(f.w);
        ((ushort4*)out)[i] = o;
    }
}

// ---------------------------------------------------------------------------
extern "C" void kernel_launch(void* const* d_in, const int* in_sizes, int n_in,
                              void* d_out, int out_size, void* d_ws, size_t ws_size,
                              hipStream_t stream)
{
    const float* x      = (const float*)d_in[0];   // [4,4096,1024]
    const float* qkv_w  = (const float*)d_in[1];   // [3072,1024]
    const float* qkv_b  = (const float*)d_in[2];   // [3072]
    const float* out_w  = (const float*)d_in[3];   // [1024,1024]
    const float* out_b  = (const float*)d_in[4];   // [1024]
    float* out = (float*)d_out;                    // [4,4096,1024] fp32

    unsigned short* W = (unsigned short*)d_ws;
    const size_t M16 = 16777216;   // one [4,4096,1024] bf16 tensor (ushorts)

    if (ws_size >= 236978176ull) {
        // ---- big mode: 226 MiB peak ----
        unsigned short* sc   = W;
        unsigned short* q    = sc + 67108864;
        unsigned short* kk   = q + M16;
        unsigned short* vT   = kk + M16;
        unsigned short* wo   = vT + M16;
        unsigned short* xb   = sc;            // transient, dead before sc write
        unsigned short* wqkv = sc + M16;      // transient
        unsigned short* ao   = q;             // q dead after scores GEMM

        cast_bf16<<<16384, 256, 0, stream>>>(x, xb, 4194304);
        cast_bf16<<<3072, 256, 0, stream>>>(qkv_w, wqkv, 786432);
        cast_bf16<<<1024, 256, 0, stream>>>(out_w, wo, 262144);

        gemm_nt<0, 0><<<12 * 64, 512, 0, stream>>>(
            xb, wqkv, 0, 0, 1024, 1024, 1024, qkv_b, q, kk, vT, 0, 0, 0.f, 12, 64);

        gemm_nt<1, 0><<<16 * 16 * 4, 512, 0, stream>>>(
            q, kk, 4194304, 4194304, 1024, 1024, 1024, nullptr,
            sc, nullptr, nullptr, 16777216, 4096, 0.03125f, 16, 16);

        softmax_rows<<<16384, 256, 0, stream>>>(sc);

        gemm_nt<2, 1><<<4 * 16 * 4, 512, 0, stream>>>(
            sc, vT, 16777216, 4194304, 4096, 4096, 4096, nullptr,
            ao, nullptr, nullptr, 4194304, 1024, 0.f, 4, 16);

        gemm_nt<3, 0><<<4 * 64, 512, 0, stream>>>(
            ao, wo, 0, 0, 1024, 1024, 1024, out_b,
            out, nullptr, nullptr, 0, 1024, 0.f, 4, 64);
    } else {
        // ---- small mode: 168 MiB peak, per-batch scores buffer ----
        unsigned short* sc   = W;
        unsigned short* q    = sc + M16;
        unsigned short* kk   = q + M16;
        unsigned short* vT   = kk + M16;
        unsigned short* ao   = vT + M16;
        unsigned short* wo   = ao + M16;
        unsigned short* wqkv = wo + 1048576;
        unsigned short* xb   = sc;

        cast_bf16<<<16384, 256, 0, stream>>>(x, xb, 4194304);
        cast_bf16<<<3072, 256, 0, stream>>>(qkv_w, wqkv, 786432);
        cast_bf16<<<1024, 256, 0, stream>>>(out_w, wo, 262144);

        gemm_nt<0, 0><<<12 * 64, 512, 0, stream>>>(
            xb, wqkv, 0, 0, 1024, 1024, 1024, qkv_b, q, kk, vT, 0, 0, 0.f, 12, 64);

        for (int z = 0; z < 4; ++z) {
            const size_t zo = (size_t)z * 4194304;
            gemm_nt<1, 0><<<16 * 16, 512, 0, stream>>>(
                q + zo, kk + zo, 0, 0, 1024, 1024, 1024, nullptr,
                sc, nullptr, nullptr, 0, 4096, 0.03125f, 16, 16);
            softmax_rows<<<4096, 256, 0, stream>>>(sc);
            gemm_nt<2, 1><<<4 * 16, 512, 0, stream>>>(
                sc, vT + zo, 0, 0, 4096, 4096, 4096, nullptr,
                ao + zo, nullptr, nullptr, 0, 1024, 0.f, 4, 16);
        }

        gemm_nt<3, 0><<<4 * 64, 512, 0, stream>>>(
            ao, wo, 0, 0, 1024, 1024, 1024, out_b,
            out, nullptr, nullptr, 0, 1024, 0.f, 4, 64);
    }
}

// Round 10
// 448.652 us; speedup vs baseline: 1.5126x; 1.0332x over previous
//
#include <hip/hip_runtime.h>
#include <hip/hip_bf16.h>

typedef __bf16 bf16x8 __attribute__((ext_vector_type(8)));
typedef float f32x4 __attribute__((ext_vector_type(4)));
typedef _Float16 h8 __attribute__((ext_vector_type(8)));
typedef unsigned short u16x8 __attribute__((ext_vector_type(8)));

__device__ inline unsigned short f2b(float x) {
    __hip_bfloat16 h = __float2bfloat16(x);
    return __builtin_bit_cast(unsigned short, h);
}

__device__ inline void gload16(const void* g, void* l) {
    __builtin_amdgcn_global_load_lds(
        (const __attribute__((address_space(1))) unsigned int*)g,
        (__attribute__((address_space(3))) unsigned int*)l, 16, 0, 0);
}

#define BAR  asm volatile("s_barrier" ::: "memory")
#define VMC(N) asm volatile("s_waitcnt vmcnt(" #N ")" ::: "memory")

// reads for one quadrant's A operands (m rows MO, MO+1; both k-halves)
#define RD_A(BASE, MO)                                                \
    af[0][0] = *(const bf16x8*)((BASE) + (MO) * 1024 + aoff0);        \
    af[0][1] = *(const bf16x8*)((BASE) + (MO) * 1024 + aoff1);        \
    af[1][0] = *(const bf16x8*)((BASE) + ((MO) + 1) * 1024 + aoff0);  \
    af[1][1] = *(const bf16x8*)((BASE) + ((MO) + 1) * 1024 + aoff1);

#define RD_B(BASE)                                                    \
    _Pragma("unroll")                                                 \
    for (int n_ = 0; n_ < 4; ++n_) {                                  \
        bfr[n_][0] = *(const bf16x8*)((BASE) + n_ * 1024 + aoff0);    \
        bfr[n_][1] = *(const bf16x8*)((BASE) + n_ * 1024 + aoff1);    \
    }

// 16 MFMA: quadrant m in {MO, MO+1} x 4 n x 2 kk, static acc indices.
// Compiler inserts the lgkm waits before first af/bfr use (rule-#18-safe).
#define MFMA_Q(MO)                                                    \
    __builtin_amdgcn_s_setprio(1);                                    \
    _Pragma("unroll")                                                 \
    for (int kk_ = 0; kk_ < 2; ++kk_)                                 \
        _Pragma("unroll")                                             \
        for (int mi_ = 0; mi_ < 2; ++mi_)                             \
            _Pragma("unroll")                                         \
            for (int n_ = 0; n_ < 4; ++n_)                            \
                acc[(MO) + mi_][n_] =                                 \
                    __builtin_amdgcn_mfma_f32_16x16x32_bf16(          \
                        af[mi_][kk_], bfr[n_][kk_],                   \
                        acc[(MO) + mi_][n_], 0, 0, 0);                \
    __builtin_amdgcn_s_setprio(0);

// ---------------------------------------------------------------------------
// NT GEMM: C[M,N] = A[M,K] * B[N,K]^T (+bias), A/B bf16 K-contiguous.
// r6 structure (verified best: 442us total, GEMM 132.5us / 46% MfmaUtil):
// 8-phase / 2-K-tile schedule, ONE barrier per phase, stage issued in the
// MFMA shadow. 256x256 tile, BK=64, 512 thr = 8 waves (2Mx4N), wave tile
// 128x64, mfma 16x16x32. LDS = 2 bufs x [A0|A1|B0|B1] x 16KiB = 128 KiB.
// Phase p: { 4 (or 12) ds_read; [seal vmcnt before BAR at p3/p7]; s_barrier;
//            stage 1 half-tile (2 gload_lds, post-barrier -> overlaps MFMA);
//            setprio(1); 16 MFMA; setprio(0) }
// Safety: a wave arrives at BAR(p+1) only after MFMA(p) issued, which is
// after its phase-p reads drained (compiler lgkm wait) -> all waves past a
// barrier implies all previous-phase reads drained; every LDS overwrite has
// >=1 phase separation from its region's last read. Stages: p0/p1: A(o);
// p2/p3: B(e+2); p4/p5: A(e+2); p6/p7: B(o+2). Seals: VMC(2) before BAR3
// (tile o landed; newest half B0(e+2) flies) and before BAR7 (tile e+2
// landed; B0(o+2) flies) — never 0 mid-loop (T4). Tail iter peeled
// (branch-free steady loop), seals VMC(0) at its p3.
// Swizzle (0-conflict, r2-verified): 16B granule g' = g ^ (row&7); source
// pre-swizzled within the row's 128B line, gload_lds dest linear, ds_read
// applies the same involution.
// SWZ=1: bijective XCD-chunk swizzle (m204; all grids %8==0 here) — puts
// consecutive wgids (which share the A panel) on one XCD's L2 (T1).
// EPI: 0 = QKV router (bias, q/k normal, v transposed), 1 = f16*scale (scores),
//      2 = bf16 (PV->ao), 3 = f32+bias (final out)
// ---------------------------------------------------------------------------
template<int EPI, int SWZ>
__global__ __launch_bounds__(512, 2) void gemm_nt(
    const unsigned short* __restrict__ A, const unsigned short* __restrict__ B,
    long aZ, long bZ, int lda, int ldb, int K,
    const float* __restrict__ bias,
    void* __restrict__ C0, void* __restrict__ C1, void* __restrict__ C2,
    long cZ, int ldc, float scale, int gx, int gy)
{
    __shared__ __attribute__((aligned(16))) unsigned short lds[2][4][8192];

    int wgid;
    if (SWZ) {
        const int nwg = (int)gridDim.x;
        const int bid = (int)blockIdx.x;
        const int qch = nwg >> 3, rch = nwg & 7;
        const int xcd = bid & 7, idx = bid >> 3;
        wgid = (xcd < rch ? xcd * (qch + 1)
                          : rch * (qch + 1) + (xcd - rch) * qch) + idx;
    } else {
        wgid = (int)blockIdx.x;
    }
    const int bx = wgid % gx;
    const int rem = wgid / gx;
    const int by = rem % gy;
    const int z = rem / gy;

    const int t = threadIdx.x;
    const int lane = t & 63, wid = t >> 6;
    const int wr = wid >> 2, wc = wid & 3;           // 2 x 4 wave grid
    const int tileM = by * 256, tileN = bx * 256;
    A += (size_t)z * aZ;
    B += (size_t)z * bZ;

    f32x4 acc[8][4] = {};

    // ---- read geometry: frag element k = kk*32 + qw*8 (qw = lane>>4);
    // granule g = kk*4+qw; physical g^(row&7), row&7 == lane&7.
    const int l4 = lane & 15, qw = lane >> 4, sw = lane & 7;
    const int aoff0 = l4 * 64 + ((qw ^ sw) << 3);
    const int aoff1 = l4 * 64 + (((4 | qw) ^ sw) << 3);

    // per-wave LDS read bases (compile-time buffer indices)
    const unsigned short* aB0 = &lds[0][wr][0];
    const unsigned short* aB1 = &lds[1][wr][0];
    const unsigned short* bB0 = &lds[0][2 + (wc >> 1)][0] + (wc & 1) * 4096;
    const unsigned short* bB1 = &lds[1][2 + (wc >> 1)][0] + (wc & 1) * 4096;

    // staging dest bases
    char* const ldsA[2] = {(char*)&lds[0][0][0], (char*)&lds[1][0][0]};
    char* const ldsB[2] = {(char*)&lds[0][2][0], (char*)&lds[1][2][0]};

    // ---- staging geometry: half-tile = 128 rows x 64 K, 2 gload16/thread.
    // row = t>>3 (+64), phys granule = t&7, src granule = (t ^ (t>>3)) & 7.
    const int srow = t >> 3;
    const int sg = ((t ^ (t >> 3)) & 7) << 3;
    const unsigned short* Asrc0 = A + (size_t)(tileM + srow) * lda + sg;
    const unsigned short* Asrc1 = Asrc0 + (size_t)128 * lda;
    const unsigned short* Bsrc0 = B + (size_t)(tileN + srow) * ldb + sg;
    const unsigned short* Bsrc1 = Bsrc0 + (size_t)128 * ldb;

    auto stageA = [&](char* Lb, int koff, int h) {
        char* dst = Lb + h * 16384 + wid * 1024;
        const unsigned short* s = (h ? Asrc1 : Asrc0) + koff;
        gload16(s, dst);
        gload16(s + (size_t)64 * lda, dst + 8192);
    };
    auto stageB = [&](char* Lb, int koff, int h) {
        char* dst = Lb + h * 16384 + wid * 1024;
        const unsigned short* s = (h ? Bsrc1 : Bsrc0) + koff;
        gload16(s, dst);
        gload16(s + (size_t)64 * ldb, dst + 8192);
    };

    const int NT = K >> 6;            // BK=64; K % 128 == 0 here -> NT even
    const int NI = NT >> 1;

    // prologue: tile0 fully + B halves of tile1; seal tile0 (B(1) flies).
    stageA(ldsA[0], 0, 0); stageA(ldsA[0], 0, 1);
    stageB(ldsB[0], 0, 0); stageB(ldsB[0], 0, 1);
    stageB(ldsB[1], 64, 0); stageB(ldsB[1], 64, 1);
    VMC(4);
    BAR;

    bf16x8 af[2][2], bfr[4][2];

#pragma unroll 1
    for (int i = 0; i < NI - 1; ++i) {
        const int kb = i * 128;
        const int ko = kb + 64, ke2 = kb + 128, ko2 = kb + 192;

        // p0
        RD_B(bB0); RD_A(aB0, 0);
        BAR; stageA(ldsA[1], ko, 0);
        MFMA_Q(0)
        // p1
        RD_A(aB0, 2);
        BAR; stageA(ldsA[1], ko, 1);
        MFMA_Q(2)
        // p2
        RD_A(aB0, 4);
        BAR; stageB(ldsB[0], ke2, 0);
        MFMA_Q(4)
        // p3: seal tile o (newest half B0(e+2) may fly)
        RD_A(aB0, 6);
        VMC(2);
        BAR; stageB(ldsB[0], ke2, 1);
        MFMA_Q(6)
        // p4
        RD_B(bB1); RD_A(aB1, 0);
        BAR; stageA(ldsA[0], ke2, 0);
        MFMA_Q(0)
        // p5
        RD_A(aB1, 2);
        BAR; stageA(ldsA[0], ke2, 1);
        MFMA_Q(2)
        // p6
        RD_A(aB1, 4);
        BAR; stageB(ldsB[1], ko2, 0);
        MFMA_Q(4)
        // p7: seal tile e+2 (newest half B0(o+2) may fly)
        RD_A(aB1, 6);
        VMC(2);
        BAR; stageB(ldsB[1], ko2, 1);
        MFMA_Q(6)
    }

    {   // ---- peeled final iteration (no future stages)
        const int ko = (NI - 1) * 128 + 64;
        RD_B(bB0); RD_A(aB0, 0);
        BAR; stageA(ldsA[1], ko, 0);
        MFMA_Q(0)
        RD_A(aB0, 2);
        BAR; stageA(ldsA[1], ko, 1);
        MFMA_Q(2)
        RD_A(aB0, 4);
        BAR;
        MFMA_Q(4)
        RD_A(aB0, 6);
        VMC(0);
        BAR;
        MFMA_Q(6)
        RD_B(bB1); RD_A(aB1, 0);
        BAR;
        MFMA_Q(0)
        RD_A(aB1, 2);
        BAR;
        MFMA_Q(2)
        RD_A(aB1, 4);
        BAR;
        MFMA_Q(4)
        RD_A(aB1, 6);
        BAR;
        MFMA_Q(6)
    }

    // epilogue: C/D layout col = lane&15, row = (lane>>4)*4 + j  [m89-verified]
    const int lr = lane >> 4, lc = lane & 15;
#pragma unroll
    for (int m = 0; m < 8; ++m) {
#pragma unroll
        for (int n = 0; n < 4; ++n) {
            f32x4 v = acc[m][n];
            const int col = tileN + wc * 64 + n * 16 + lc;
            const int row0 = tileM + wr * 128 + m * 16 + lr * 4;
            if (EPI == 0) {
                const float bv = bias[col];
                if (col < 2048) {
                    unsigned short* dst = (col < 1024) ? (unsigned short*)C0
                                                       : (unsigned short*)C1;
                    const int cc = col & 1023;
#pragma unroll
                    for (int j = 0; j < 4; ++j)
                        dst[(size_t)(row0 + j) * 1024 + cc] = f2b(v[j] + bv);
                } else {
                    // vT[b][col-2048][s], rows row0..row0+3 are consecutive s
                    const int b = row0 >> 12, s = row0 & 4095;
                    ushort4 h4;
                    h4.x = f2b(v[0] + bv); h4.y = f2b(v[1] + bv);
                    h4.z = f2b(v[2] + bv); h4.w = f2b(v[3] + bv);
                    *(ushort4*)((unsigned short*)C2 +
                                ((size_t)b * 1024 + (col - 2048)) * 4096 + s) = h4;
                }
            } else if (EPI == 1) {
#pragma unroll
                for (int j = 0; j < 4; ++j)
                    ((_Float16*)C0)[(size_t)z * cZ + (size_t)(row0 + j) * ldc + col] =
                        (_Float16)(v[j] * scale);
            } else if (EPI == 2) {
#pragma unroll
                for (int j = 0; j < 4; ++j)
                    ((unsigned short*)C0)[(size_t)z * cZ + (size_t)(row0 + j) * ldc + col] =
                        f2b(v[j]);
            } else {
#pragma unroll
                for (int j = 0; j < 4; ++j)
                    ((float*)C0)[(size_t)(row0 + j) * ldc + col] = v[j] + bias[col];
            }
        }
    }
}

// ---------------------------------------------------------------------------
// Row softmax in-place: reads 4096 f16, writes 4096 bf16 over the same bytes.
// __expf: v_exp_f32-based (~2^-21 rel err, invisible at bf16 output).
// ---------------------------------------------------------------------------
__global__ __launch_bounds__(256) void softmax_rows(unsigned short* __restrict__ sc)
{
    const size_t rowoff = (size_t)blockIdx.x * 4096;
    const int t = threadIdx.x;

    h8 a = *(const h8*)(sc + rowoff + t * 8);
    h8 b = *(const h8*)(sc + rowoff + 2048 + t * 8);
    float v[16];
#pragma unroll
    for (int i = 0; i < 8; ++i) { v[i] = (float)a[i]; v[8 + i] = (float)b[i]; }

    float mx = -1e30f;
#pragma unroll
    for (int i = 0; i < 16; ++i) mx = fmaxf(mx, v[i]);
#pragma unroll
    for (int o = 32; o > 0; o >>= 1) mx = fmaxf(mx, __shfl_xor(mx, o));
    __shared__ float redm[4];
    if ((t & 63) == 0) redm[t >> 6] = mx;
    __syncthreads();
    mx = fmaxf(fmaxf(redm[0], redm[1]), fmaxf(redm[2], redm[3]));

    float sum = 0.f;
#pragma unroll
    for (int i = 0; i < 16; ++i) { v[i] = __expf(v[i] - mx); sum += v[i]; }
#pragma unroll
    for (int o = 32; o > 0; o >>= 1) sum += __shfl_xor(sum, o);
    __shared__ float reds[4];
    if ((t & 63) == 0) reds[t >> 6] = sum;
    __syncthreads();
    sum = reds[0] + reds[1] + reds[2] + reds[3];
    const float rs = 1.f / sum;

    u16x8 w0, w1;
#pragma unroll
    for (int i = 0; i < 8; ++i) {
        w0[i] = f2b(v[i] * rs);
        w1[i] = f2b(v[8 + i] * rs);
    }
    *(u16x8*)(sc + rowoff + t * 8) = w0;
    *(u16x8*)(sc + rowoff + 2048 + t * 8) = w1;
}

__global__ __launch_bounds__(256) void cast_bf16(
    const float* __restrict__ in, unsigned short* __restrict__ out, int n4)
{
    const int i = blockIdx.x * 256 + threadIdx.x;
    if (i < n4) {
        float4 f = ((const float4*)in)[i];
        ushort4 o;
        o.x = f2b(f.x); o.y = f2b(f.y); o.z = f2b(f.z); o.w = f2b(f.w);
        ((ushort4*)out)[i] = o;
    }
}

// ---------------------------------------------------------------------------
extern "C" void kernel_launch(void* const* d_in, const int* in_sizes, int n_in,
                              void* d_out, int out_size, void* d_ws, size_t ws_size,
                              hipStream_t stream)
{
    const float* x      = (const float*)d_in[0];   // [4,4096,1024]
    const float* qkv_w  = (const float*)d_in[1];   // [3072,1024]
    const float* qkv_b  = (const float*)d_in[2];   // [3072]
    const float* out_w  = (const float*)d_in[3];   // [1024,1024]
    const float* out_b  = (const float*)d_in[4];   // [1024]
    float* out = (float*)d_out;                    // [4,4096,1024] fp32

    unsigned short* W = (unsigned short*)d_ws;
    const size_t M16 = 16777216;   // one [4,4096,1024] bf16 tensor (ushorts)

    if (ws_size >= 236978176ull) {
        // ---- big mode: 226 MiB peak ----
        unsigned short* sc   = W;
        unsigned short* q    = sc + 67108864;
        unsigned short* kk   = q + M16;
        unsigned short* vT   = kk + M16;
        unsigned short* wo   = vT + M16;
        unsigned short* xb   = sc;            // transient, dead before sc write
        unsigned short* wqkv = sc + M16;      // transient
        unsigned short* ao   = q;             // q dead after scores GEMM

        cast_bf16<<<16384, 256, 0, stream>>>(x, xb, 4194304);
        cast_bf16<<<3072, 256, 0, stream>>>(qkv_w, wqkv, 786432);
        cast_bf16<<<1024, 256, 0, stream>>>(out_w, wo, 262144);

        gemm_nt<0, 1><<<12 * 64, 512, 0, stream>>>(
            xb, wqkv, 0, 0, 1024, 1024, 1024, qkv_b, q, kk, vT, 0, 0, 0.f, 12, 64);

        gemm_nt<1, 1><<<16 * 16 * 4, 512, 0, stream>>>(
            q, kk, 4194304, 4194304, 1024, 1024, 1024, nullptr,
            sc, nullptr, nullptr, 16777216, 4096, 0.03125f, 16, 16);

        softmax_rows<<<16384, 256, 0, stream>>>(sc);

        gemm_nt<2, 1><<<4 * 16 * 4, 512, 0, stream>>>(
            sc, vT, 16777216, 4194304, 4096, 4096, 4096, nullptr,
            ao, nullptr, nullptr, 4194304, 1024, 0.f, 4, 16);

        gemm_nt<3, 1><<<4 * 64, 512, 0, stream>>>(
            ao, wo, 0, 0, 1024, 1024, 1024, out_b,
            out, nullptr, nullptr, 0, 1024, 0.f, 4, 64);
    } else {
        // ---- small mode: 168 MiB peak, per-batch scores buffer ----
        unsigned short* sc   = W;
        unsigned short* q    = sc + M16;
        unsigned short* kk   = q + M16;
        unsigned short* vT   = kk + M16;
        unsigned short* ao   = vT + M16;
        unsigned short* wo   = ao + M16;
        unsigned short* wqkv = wo + 1048576;
        unsigned short* xb   = sc;

        cast_bf16<<<16384, 256, 0, stream>>>(x, xb, 4194304);
        cast_bf16<<<3072, 256, 0, stream>>>(qkv_w, wqkv, 786432);
        cast_bf16<<<1024, 256, 0, stream>>>(out_w, wo, 262144);

        gemm_nt<0, 1><<<12 * 64, 512, 0, stream>>>(
            xb, wqkv, 0, 0, 1024, 1024, 1024, qkv_b, q, kk, vT, 0, 0, 0.f, 12, 64);

        for (int z = 0; z < 4; ++z) {
            const size_t zo = (size_t)z * 4194304;
            gemm_nt<1, 1><<<16 * 16, 512, 0, stream>>>(
                q + zo, kk + zo, 0, 0, 1024, 1024, 1024, nullptr,
                sc, nullptr, nullptr, 0, 4096, 0.03125f, 16, 16);
            softmax_rows<<<4096, 256, 0, stream>>>(sc);
            gemm_nt<2, 1><<<4 * 16, 512, 0, stream>>>(
                sc, vT + zo, 0, 0, 4096, 4096, 4096, nullptr,
                ao + zo, nullptr, nullptr, 0, 1024, 0.f, 4, 16);
        }

        gemm_nt<3, 1><<<4 * 64, 512, 0, stream>>>(
            ao, wo, 0, 0, 1024, 1024, 1024, out_b,
            out, nullptr, nullptr, 0, 1024, 0.f, 4, 64);
    }
}